// Round 3
// baseline (251.805 us; speedup 1.0000x reference)
//
#include <hip/hip_runtime.h>
#include <stdint.h>

#define D 128
#define K_NEI 10
#define TILE_M 64

typedef __bf16 bf16x8 __attribute__((ext_vector_type(8)));
typedef float f32x4 __attribute__((ext_vector_type(4)));

__device__ __forceinline__ uint32_t f2bf(float f) {
    union { float f; uint32_t u; } v; v.f = f;
    uint32_t u = v.u;
    return (u + 0x7FFFu + ((u >> 16) & 1u)) >> 16;   // RNE
}
__device__ __forceinline__ float bf2f(uint32_t h) {
    union { uint32_t u; float f; } v; v.u = h << 16; return v.f;
}
__device__ __forceinline__ uint32_t pack2(float a, float b) {
    return f2bf(a) | (f2bf(b) << 16);
}

// One block computes out[G..G+63][0..127] = relu([self | agg] @ W^T)
// FEATS_F32: feats rows are fp32[128] (layer 1) vs bf16[128] (layer 2 reading h1)
// OUT_F32:   store fp32 (layer 2 -> d_out) vs bf16 (layer 1 -> h1 in ws)
// W: [128][256] fp32 row-major (k-contiguous == B^T); converted to bf16 at staging.
// 256 threads = 4 waves; wave w owns output rows w*16..w*16+15.
// LDS: A-tile 64x128 bf16 (16 KB) + W-half 128x128 bf16 (32 KB) = 48 KB.
template <bool FEATS_F32, bool OUT_F32>
__global__ void sage_layer(const void* __restrict__ feats_,
                           const float* __restrict__ W,
                           const int* __restrict__ self_idx,
                           const int* __restrict__ neigh_idx,
                           void* __restrict__ out_)
{
    __shared__ __align__(16) uint16_t Alds[TILE_M * 128];  // 16 KB
    __shared__ __align__(16) uint16_t Wlds[128 * 128];     // 32 KB

    const int tid  = threadIdx.x;
    const int wave = tid >> 6;
    const int lane = tid & 63;
    const int r16  = lane & 15;
    const int q    = lane >> 4;
    const int G    = blockIdx.x * TILE_M;

    const float*    feats_f = (const float*)feats_;
    const uint16_t* feats_b = (const uint16_t*)feats_;

    f32x4 acc[8];
    #pragma unroll
    for (int nt = 0; nt < 8; ++nt) acc[nt] = (f32x4){0.f, 0.f, 0.f, 0.f};

    for (int half = 0; half < 2; ++half) {
        // ---- stage W half (fp32 -> bf16), XOR-swizzled 16B chunks
        #pragma unroll
        for (int it = 0; it < 8; ++it) {
            int t = it * 256 + tid;
            int j = t >> 4, c = t & 15;          // j: row 0..127, c: chunk 0..15 (8 bf16)
            const float* src = W + (size_t)j * 256 + half * 128 + c * 8;
            f32x4 w0 = *(const f32x4*)(src);
            f32x4 w1 = *(const f32x4*)(src + 4);
            uint4 o;
            o.x = pack2(w0[0], w0[1]); o.y = pack2(w0[2], w0[3]);
            o.z = pack2(w1[0], w1[1]); o.w = pack2(w1[2], w1[3]);
            int cs = c ^ (j & 15);
            *(uint4*)(Wlds + j * 128 + cs * 8) = o;
        }
        if (half == 0) {
            // ---- A half 0: self features (gather + convert)
            #pragma unroll
            for (int it = 0; it < 4; ++it) {
                int t = it * 256 + tid;
                int n = t >> 4, c = t & 15;
                int node = self_idx[G + n];
                uint4 o;
                if (FEATS_F32) {
                    const float* src = feats_f + (size_t)node * D + c * 8;
                    f32x4 f0 = *(const f32x4*)(src);
                    f32x4 f1 = *(const f32x4*)(src + 4);
                    o.x = pack2(f0[0], f0[1]); o.y = pack2(f0[2], f0[3]);
                    o.z = pack2(f1[0], f1[1]); o.w = pack2(f1[2], f1[3]);
                } else {
                    o = *(const uint4*)(feats_b + (size_t)node * D + c * 8);
                }
                int cs = c ^ (n & 15);
                *(uint4*)(Alds + n * 128 + cs * 8) = o;
            }
        } else {
            // ---- A half 1: mean over K=10 neighbor rows (fp32 accumulate)
            #pragma unroll
            for (int it = 0; it < 4; ++it) {
                int t = it * 256 + tid;
                int n = t >> 4, c = t & 15;
                const int* nrow = neigh_idx + (size_t)(G + n) * K_NEI;
                float s0=0,s1=0,s2=0,s3=0,s4=0,s5=0,s6=0,s7=0;
                #pragma unroll
                for (int k = 0; k < K_NEI; ++k) {
                    if (FEATS_F32) {
                        const float* src = feats_f + (size_t)nrow[k] * D + c * 8;
                        f32x4 f0 = *(const f32x4*)(src);
                        f32x4 f1 = *(const f32x4*)(src + 4);
                        s0 += f0[0]; s1 += f0[1]; s2 += f0[2]; s3 += f0[3];
                        s4 += f1[0]; s5 += f1[1]; s6 += f1[2]; s7 += f1[3];
                    } else {
                        uint4 v = *(const uint4*)(feats_b + (size_t)nrow[k] * D + c * 8);
                        s0 += bf2f(v.x & 0xFFFFu); s1 += bf2f(v.x >> 16);
                        s2 += bf2f(v.y & 0xFFFFu); s3 += bf2f(v.y >> 16);
                        s4 += bf2f(v.z & 0xFFFFu); s5 += bf2f(v.z >> 16);
                        s6 += bf2f(v.w & 0xFFFFu); s7 += bf2f(v.w >> 16);
                    }
                }
                const float inv = 0.1f;
                uint4 o;
                o.x = pack2(s0 * inv, s1 * inv);
                o.y = pack2(s2 * inv, s3 * inv);
                o.z = pack2(s4 * inv, s5 * inv);
                o.w = pack2(s6 * inv, s7 * inv);
                int cs = c ^ (n & 15);
                *(uint4*)(Alds + n * 128 + cs * 8) = o;
            }
        }
        __syncthreads();

        // ---- MFMA over this 128-wide K half: 4 k-steps of 32
        #pragma unroll
        for (int ks = 0; ks < 4; ++ks) {
            int cidx = ks * 4 + q;               // 16B chunk 0..15; local k = q*8+j
            bf16x8 a = *(const bf16x8*)(Alds + (wave * 16 + r16) * 128 + ((cidx ^ r16) * 8));
            bf16x8 b[8];
            #pragma unroll
            for (int nt = 0; nt < 8; ++nt) {
                int j = nt * 16 + r16;           // W row = output col
                b[nt] = *(const bf16x8*)(Wlds + j * 128 + ((cidx ^ r16) * 8));
            }
            #pragma unroll
            for (int nt = 0; nt < 8; ++nt)
                acc[nt] = __builtin_amdgcn_mfma_f32_16x16x32_bf16(a, b[nt], acc[nt], 0, 0, 0);
        }
        __syncthreads();
    }

    // ---- epilogue: relu + store. C/D layout: col=lane&15, row=q*4+reg
    const int row_base = G + wave * 16 + q * 4;
    #pragma unroll
    for (int nt = 0; nt < 8; ++nt) {
        int col = nt * 16 + r16;
        #pragma unroll
        for (int r = 0; r < 4; ++r) {
            float v = acc[nt][r];
            v = v > 0.f ? v : 0.f;
            if (OUT_F32) ((float*)out_)[(size_t)(row_base + r) * D + col] = v;
            else ((uint16_t*)out_)[(size_t)(row_base + r) * D + col] = (uint16_t)f2bf(v);
        }
    }
}

// Sentinel: distinguishes "launches broken" from "compute wrong" if R3 fails.
// Layer 2 overwrites this element, so it is invisible when the pipeline works.
__global__ void probe(float* p) { *p = 12345.0f; }

extern "C" void kernel_launch(void* const* d_in, const int* in_sizes, int n_in,
                              void* d_out, int out_size, void* d_ws, size_t ws_size,
                              hipStream_t stream) {
    const float* raw = (const float*)d_in[0];          // [200000][128] fp32
    const float* W1  = (const float*)d_in[1];          // [128][256] fp32
    const float* W2  = (const float*)d_in[2];          // [128][256] fp32
    const int* layer1_nodes = (const int*)d_in[3];     // [81920]
    const int* neigh0       = (const int*)d_in[4];     // [81920][10]
    const int* map_batch    = (const int*)d_in[5];     // [8192]
    const int* neigh1       = (const int*)d_in[6];     // [8192][10]

    uint16_t* h1 = (uint16_t*)d_ws;                    // [81920][128] bf16 = 21 MB

    const int N1 = in_sizes[3];      // 81920
    const int B  = in_sizes[5];      // 8192

    probe<<<1, 1, 0, stream>>>((float*)d_out + (out_size - 1));
    sage_layer<true,  false><<<N1 / TILE_M, 256, 0, stream>>>(raw, W1, layer1_nodes, neigh0, h1);
    sage_layer<false, true ><<<B  / TILE_M, 256, 0, stream>>>(h1,  W2, map_batch,    neigh1, d_out);
}

// Round 4
// 246.561 us; speedup vs baseline: 1.0213x; 1.0213x over previous
//
#include <hip/hip_runtime.h>
#include <stdint.h>

#define D 128
#define K_NEI 10
#define TILE_M 64

typedef __bf16 bf16x8 __attribute__((ext_vector_type(8)));
typedef float f32x4 __attribute__((ext_vector_type(4)));

__device__ __forceinline__ uint32_t f2bf(float f) {
    union { float f; uint32_t u; } v; v.f = f;
    uint32_t u = v.u;
    return (u + 0x7FFFu + ((u >> 16) & 1u)) >> 16;   // RNE
}
__device__ __forceinline__ float bf2f(uint32_t h) {
    union { uint32_t u; float f; } v; v.u = h << 16; return v.f;
}
__device__ __forceinline__ uint32_t pack2(float a, float b) {
    return f2bf(a) | (f2bf(b) << 16);
}

// ============================================================================
// build_A: gather + mean aggregate, no LDS, full occupancy.
// 16 threads per node; thread j owns output chunk j (8 elems).
// Writes A[i][0:128] = feats[self_idx[i]], A[i][128:256] = mean_k feats[nbr_k].
// A rows are bf16[256] (512 B).
// ============================================================================
template <bool FEATS_F32>
__global__ void build_A(const void* __restrict__ feats_,
                        const int* __restrict__ self_idx,
                        const int* __restrict__ neigh_idx,
                        uint16_t* __restrict__ A, int M)
{
    const int t = blockIdx.x * 256 + threadIdx.x;
    const int i = t >> 4;          // node
    const int j = t & 15;          // chunk 0..15
    if (i >= M) return;

    const float*    ff = (const float*)feats_;
    const uint16_t* fb = (const uint16_t*)feats_;

    // ---- self copy
    {
        int node = self_idx[i];
        uint4 o;
        if (FEATS_F32) {
            const float* src = ff + (size_t)node * D + j * 8;
            f32x4 a = *(const f32x4*)src;
            f32x4 b = *(const f32x4*)(src + 4);
            o.x = pack2(a[0], a[1]); o.y = pack2(a[2], a[3]);
            o.z = pack2(b[0], b[1]); o.w = pack2(b[2], b[3]);
        } else {
            o = *(const uint4*)(fb + (size_t)node * D + j * 8);
        }
        *(uint4*)(A + (size_t)i * 256 + j * 8) = o;
    }

    // ---- neighbor mean
    const int* nrow = neigh_idx + (size_t)i * K_NEI;
    int idx[K_NEI];
    #pragma unroll
    for (int k = 0; k < K_NEI; ++k) idx[k] = nrow[k];

    float s0=0,s1=0,s2=0,s3=0,s4=0,s5=0,s6=0,s7=0;
    #pragma unroll
    for (int k = 0; k < K_NEI; ++k) {
        if (FEATS_F32) {
            const float* src = ff + (size_t)idx[k] * D + j * 8;
            f32x4 a = *(const f32x4*)src;
            f32x4 b = *(const f32x4*)(src + 4);
            s0 += a[0]; s1 += a[1]; s2 += a[2]; s3 += a[3];
            s4 += b[0]; s5 += b[1]; s6 += b[2]; s7 += b[3];
        } else {
            uint4 v = *(const uint4*)(fb + (size_t)idx[k] * D + j * 8);
            s0 += bf2f(v.x & 0xFFFFu); s1 += bf2f(v.x >> 16);
            s2 += bf2f(v.y & 0xFFFFu); s3 += bf2f(v.y >> 16);
            s4 += bf2f(v.z & 0xFFFFu); s5 += bf2f(v.z >> 16);
            s6 += bf2f(v.w & 0xFFFFu); s7 += bf2f(v.w >> 16);
        }
    }
    const float inv = 0.1f;
    uint4 o;
    o.x = pack2(s0 * inv, s1 * inv);
    o.y = pack2(s2 * inv, s3 * inv);
    o.z = pack2(s4 * inv, s5 * inv);
    o.w = pack2(s6 * inv, s7 * inv);
    *(uint4*)(A + (size_t)i * 256 + 128 + j * 8) = o;
}

// ============================================================================
// gemm_relu: out[G..G+63][0..127] = relu(A[G..G+63][0:256] @ W^T)
// A: [M][256] bf16 contiguous. W: [128][256] fp32 row-major (k-contiguous).
// Proven R3 MFMA addressing; A staging is now contiguous loads.
// ============================================================================
template <bool OUT_F32>
__global__ void gemm_relu(const uint16_t* __restrict__ A,
                          const float* __restrict__ W,
                          void* __restrict__ out_)
{
    __shared__ __align__(16) uint16_t Alds[TILE_M * 128];  // 16 KB
    __shared__ __align__(16) uint16_t Wlds[128 * 128];     // 32 KB

    const int tid  = threadIdx.x;
    const int wave = tid >> 6;
    const int lane = tid & 63;
    const int r16  = lane & 15;
    const int q    = lane >> 4;
    const int G    = blockIdx.x * TILE_M;

    f32x4 acc[8];
    #pragma unroll
    for (int nt = 0; nt < 8; ++nt) acc[nt] = (f32x4){0.f, 0.f, 0.f, 0.f};

    for (int half = 0; half < 2; ++half) {
        // stage W half (fp32 -> bf16), XOR-swizzled 16B chunks
        #pragma unroll
        for (int it = 0; it < 8; ++it) {
            int t = it * 256 + tid;
            int j = t >> 4, c = t & 15;
            const float* src = W + (size_t)j * 256 + half * 128 + c * 8;
            f32x4 w0 = *(const f32x4*)(src);
            f32x4 w1 = *(const f32x4*)(src + 4);
            uint4 o;
            o.x = pack2(w0[0], w0[1]); o.y = pack2(w0[2], w0[3]);
            o.z = pack2(w1[0], w1[1]); o.w = pack2(w1[2], w1[3]);
            int cs = c ^ (j & 15);
            *(uint4*)(Wlds + j * 128 + cs * 8) = o;
        }
        // stage A half: contiguous rows
        #pragma unroll
        for (int it = 0; it < 4; ++it) {
            int t = it * 256 + tid;
            int n = t >> 4, c = t & 15;
            uint4 v = *(const uint4*)(A + (size_t)(G + n) * 256 + half * 128 + c * 8);
            int cs = c ^ (n & 15);
            *(uint4*)(Alds + n * 128 + cs * 8) = v;
        }
        __syncthreads();

        #pragma unroll
        for (int ks = 0; ks < 4; ++ks) {
            int cidx = ks * 4 + q;
            bf16x8 a = *(const bf16x8*)(Alds + (wave * 16 + r16) * 128 + ((cidx ^ r16) * 8));
            bf16x8 b[8];
            #pragma unroll
            for (int nt = 0; nt < 8; ++nt) {
                int jj = nt * 16 + r16;
                b[nt] = *(const bf16x8*)(Wlds + jj * 128 + ((cidx ^ r16) * 8));
            }
            #pragma unroll
            for (int nt = 0; nt < 8; ++nt)
                acc[nt] = __builtin_amdgcn_mfma_f32_16x16x32_bf16(a, b[nt], acc[nt], 0, 0, 0);
        }
        __syncthreads();
    }

    const int row_base = G + wave * 16 + q * 4;
    #pragma unroll
    for (int nt = 0; nt < 8; ++nt) {
        int col = nt * 16 + r16;
        #pragma unroll
        for (int r = 0; r < 4; ++r) {
            float v = acc[nt][r];
            v = v > 0.f ? v : 0.f;
            if (OUT_F32) ((float*)out_)[(size_t)(row_base + r) * D + col] = v;
            else ((uint16_t*)out_)[(size_t)(row_base + r) * D + col] = (uint16_t)f2bf(v);
        }
    }
}

// ============================================================================
// Fallback (R3's fused kernel) — used only if ws_size < 64 MiB.
// ============================================================================
template <bool FEATS_F32, bool OUT_F32>
__global__ void sage_layer(const void* __restrict__ feats_,
                           const float* __restrict__ W,
                           const int* __restrict__ self_idx,
                           const int* __restrict__ neigh_idx,
                           void* __restrict__ out_)
{
    __shared__ __align__(16) uint16_t Alds[TILE_M * 128];
    __shared__ __align__(16) uint16_t Wlds[128 * 128];

    const int tid  = threadIdx.x;
    const int wave = tid >> 6;
    const int lane = tid & 63;
    const int r16  = lane & 15;
    const int q    = lane >> 4;
    const int G    = blockIdx.x * TILE_M;

    const float*    feats_f = (const float*)feats_;
    const uint16_t* feats_b = (const uint16_t*)feats_;

    f32x4 acc[8];
    #pragma unroll
    for (int nt = 0; nt < 8; ++nt) acc[nt] = (f32x4){0.f, 0.f, 0.f, 0.f};

    for (int half = 0; half < 2; ++half) {
        #pragma unroll
        for (int it = 0; it < 8; ++it) {
            int t = it * 256 + tid;
            int j = t >> 4, c = t & 15;
            const float* src = W + (size_t)j * 256 + half * 128 + c * 8;
            f32x4 w0 = *(const f32x4*)(src);
            f32x4 w1 = *(const f32x4*)(src + 4);
            uint4 o;
            o.x = pack2(w0[0], w0[1]); o.y = pack2(w0[2], w0[3]);
            o.z = pack2(w1[0], w1[1]); o.w = pack2(w1[2], w1[3]);
            int cs = c ^ (j & 15);
            *(uint4*)(Wlds + j * 128 + cs * 8) = o;
        }
        if (half == 0) {
            #pragma unroll
            for (int it = 0; it < 4; ++it) {
                int t = it * 256 + tid;
                int n = t >> 4, c = t & 15;
                int node = self_idx[G + n];
                uint4 o;
                if (FEATS_F32) {
                    const float* src = feats_f + (size_t)node * D + c * 8;
                    f32x4 f0 = *(const f32x4*)(src);
                    f32x4 f1 = *(const f32x4*)(src + 4);
                    o.x = pack2(f0[0], f0[1]); o.y = pack2(f0[2], f0[3]);
                    o.z = pack2(f1[0], f1[1]); o.w = pack2(f1[2], f1[3]);
                } else {
                    o = *(const uint4*)(feats_b + (size_t)node * D + c * 8);
                }
                int cs = c ^ (n & 15);
                *(uint4*)(Alds + n * 128 + cs * 8) = o;
            }
        } else {
            #pragma unroll
            for (int it = 0; it < 4; ++it) {
                int t = it * 256 + tid;
                int n = t >> 4, c = t & 15;
                const int* nrow = neigh_idx + (size_t)(G + n) * K_NEI;
                float s0=0,s1=0,s2=0,s3=0,s4=0,s5=0,s6=0,s7=0;
                #pragma unroll
                for (int k = 0; k < K_NEI; ++k) {
                    if (FEATS_F32) {
                        const float* src = feats_f + (size_t)nrow[k] * D + c * 8;
                        f32x4 f0 = *(const f32x4*)(src);
                        f32x4 f1 = *(const f32x4*)(src + 4);
                        s0 += f0[0]; s1 += f0[1]; s2 += f0[2]; s3 += f0[3];
                        s4 += f1[0]; s5 += f1[1]; s6 += f1[2]; s7 += f1[3];
                    } else {
                        uint4 v = *(const uint4*)(feats_b + (size_t)nrow[k] * D + c * 8);
                        s0 += bf2f(v.x & 0xFFFFu); s1 += bf2f(v.x >> 16);
                        s2 += bf2f(v.y & 0xFFFFu); s3 += bf2f(v.y >> 16);
                        s4 += bf2f(v.z & 0xFFFFu); s5 += bf2f(v.z >> 16);
                        s6 += bf2f(v.w & 0xFFFFu); s7 += bf2f(v.w >> 16);
                    }
                }
                const float inv = 0.1f;
                uint4 o;
                o.x = pack2(s0 * inv, s1 * inv);
                o.y = pack2(s2 * inv, s3 * inv);
                o.z = pack2(s4 * inv, s5 * inv);
                o.w = pack2(s6 * inv, s7 * inv);
                int cs = c ^ (n & 15);
                *(uint4*)(Alds + n * 128 + cs * 8) = o;
            }
        }
        __syncthreads();

        #pragma unroll
        for (int ks = 0; ks < 4; ++ks) {
            int cidx = ks * 4 + q;
            bf16x8 a = *(const bf16x8*)(Alds + (wave * 16 + r16) * 128 + ((cidx ^ r16) * 8));
            bf16x8 b[8];
            #pragma unroll
            for (int nt = 0; nt < 8; ++nt) {
                int jj = nt * 16 + r16;
                b[nt] = *(const bf16x8*)(Wlds + jj * 128 + ((cidx ^ r16) * 8));
            }
            #pragma unroll
            for (int nt = 0; nt < 8; ++nt)
                acc[nt] = __builtin_amdgcn_mfma_f32_16x16x32_bf16(a, b[nt], acc[nt], 0, 0, 0);
        }
        __syncthreads();
    }

    const int row_base = G + wave * 16 + q * 4;
    #pragma unroll
    for (int nt = 0; nt < 8; ++nt) {
        int col = nt * 16 + r16;
        #pragma unroll
        for (int r = 0; r < 4; ++r) {
            float v = acc[nt][r];
            v = v > 0.f ? v : 0.f;
            if (OUT_F32) ((float*)out_)[(size_t)(row_base + r) * D + col] = v;
            else ((uint16_t*)out_)[(size_t)(row_base + r) * D + col] = (uint16_t)f2bf(v);
        }
    }
}

extern "C" void kernel_launch(void* const* d_in, const int* in_sizes, int n_in,
                              void* d_out, int out_size, void* d_ws, size_t ws_size,
                              hipStream_t stream) {
    const float* raw = (const float*)d_in[0];          // [200000][128] fp32
    const float* W1  = (const float*)d_in[1];          // [128][256] fp32
    const float* W2  = (const float*)d_in[2];          // [128][256] fp32
    const int* layer1_nodes = (const int*)d_in[3];     // [81920]
    const int* neigh0       = (const int*)d_in[4];     // [81920][10]
    const int* map_batch    = (const int*)d_in[5];     // [8192]
    const int* neigh1       = (const int*)d_in[6];     // [8192][10]

    const int N1 = in_sizes[3];      // 81920
    const int B  = in_sizes[5];      // 8192

    // ws layout: A1 [N1][256] bf16 | h1 [N1][128] bf16 | A2 [B][256] bf16
    const size_t needed = (size_t)N1 * 256 * 2 + (size_t)N1 * 128 * 2 + (size_t)B * 256 * 2;

    if (ws_size >= needed) {
        uint16_t* A1 = (uint16_t*)d_ws;
        uint16_t* h1 = A1 + (size_t)N1 * 256;
        uint16_t* A2 = h1 + (size_t)N1 * 128;

        build_A<true ><<<(N1 * 16 + 255) / 256, 256, 0, stream>>>(raw, layer1_nodes, neigh0, A1, N1);
        gemm_relu<false><<<N1 / TILE_M, 256, 0, stream>>>(A1, W1, h1);
        build_A<false><<<(B * 16 + 255) / 256, 256, 0, stream>>>(h1, map_batch, neigh1, A2, B);
        gemm_relu<true ><<<B / TILE_M, 256, 0, stream>>>(A2, W2, d_out);
    } else {
        // fallback: R3 fused path (needs only h1 = N1*128*2 bytes)
        uint16_t* h1 = (uint16_t*)d_ws;
        sage_layer<true,  false><<<N1 / TILE_M, 256, 0, stream>>>(raw, W1, layer1_nodes, neigh0, h1);
        sage_layer<false, true ><<<B  / TILE_M, 256, 0, stream>>>(h1,  W2, map_batch,    neigh1, d_out);
    }
}

// Round 5
// 244.551 us; speedup vs baseline: 1.0297x; 1.0082x over previous
//
#include <hip/hip_runtime.h>
#include <stdint.h>

#define D 128
#define K_NEI 10
#define TILE_M 64

typedef __bf16 bf16x8 __attribute__((ext_vector_type(8)));
typedef float f32x4 __attribute__((ext_vector_type(4)));

__device__ __forceinline__ uint32_t f2bf(float f) {
    union { float f; uint32_t u; } v; v.f = f;
    uint32_t u = v.u;
    return (u + 0x7FFFu + ((u >> 16) & 1u)) >> 16;   // RNE
}
__device__ __forceinline__ float bf2f(uint32_t h) {
    union { uint32_t u; float f; } v; v.u = h << 16; return v.f;
}
__device__ __forceinline__ uint32_t pack2(float a, float b) {
    return f2bf(a) | (f2bf(b) << 16);
}

// ============================================================================
// convert_W: W [128][256] fp32 -> Wb [256][128] bf16, where
// Wb[c][k] = W[c & 127][(c>>7)*128 + k].  (c<128: Wl rows; c>=128: Wr rows)
// grid: 16 blocks x 256 thr, each thread converts 8 elems.
// ============================================================================
__global__ void convert_W(const float* __restrict__ W, uint16_t* __restrict__ Wb)
{
    int t = blockIdx.x * 256 + threadIdx.x;   // 0..4095
    int c = t >> 4, j = t & 15;
    const float* src = W + (size_t)(c & 127) * 256 + (c >> 7) * 128 + j * 8;
    f32x4 a = *(const f32x4*)src;
    f32x4 b = *(const f32x4*)(src + 4);
    uint4 o;
    o.x = pack2(a[0], a[1]); o.y = pack2(a[2], a[3]);
    o.z = pack2(b[0], b[1]); o.w = pack2(b[2], b[3]);
    *(uint4*)(Wb + (size_t)c * 128 + j * 8) = o;
}

// ============================================================================
// gemm_P: P[G..G+63][0..255] = A[G..G+63][0:128] @ Wb^T   (no relu, bf16 out)
// A rows contiguous (streaming!): fp32 (raw) or bf16 (h1). Wb: [256][128] bf16.
// Proven R3/R4 MFMA addressing; K=128 staged once, N in two 128-col halves.
// LDS 48 KB -> 3 blocks/CU.
// ============================================================================
template <bool A_F32>
__global__ void gemm_P(const void* __restrict__ Asrc_,
                       const uint16_t* __restrict__ Wb,
                       uint16_t* __restrict__ P)
{
    __shared__ __align__(16) uint16_t Alds[TILE_M * 128];  // 16 KB
    __shared__ __align__(16) uint16_t Wlds[128 * 128];     // 32 KB

    const int tid  = threadIdx.x;
    const int wave = tid >> 6;
    const int lane = tid & 63;
    const int r16  = lane & 15;
    const int q    = lane >> 4;
    const int G    = blockIdx.x * TILE_M;

    // ---- stage A (full K=128) once: contiguous rows G..G+63
    #pragma unroll
    for (int it = 0; it < 4; ++it) {
        int t = it * 256 + tid;
        int n = t >> 4, c = t & 15;
        uint4 o;
        if (A_F32) {
            const float* src = (const float*)Asrc_ + (size_t)(G + n) * D + c * 8;
            f32x4 a = *(const f32x4*)src;
            f32x4 b = *(const f32x4*)(src + 4);
            o.x = pack2(a[0], a[1]); o.y = pack2(a[2], a[3]);
            o.z = pack2(b[0], b[1]); o.w = pack2(b[2], b[3]);
        } else {
            o = *(const uint4*)((const uint16_t*)Asrc_ + (size_t)(G + n) * D + c * 8);
        }
        int cs = c ^ (n & 15);
        *(uint4*)(Alds + n * 128 + cs * 8) = o;
    }

    f32x4 acc[2][8];
    #pragma unroll
    for (int h = 0; h < 2; ++h)
        #pragma unroll
        for (int nt = 0; nt < 8; ++nt) acc[h][nt] = (f32x4){0.f, 0.f, 0.f, 0.f};

    for (int h = 0; h < 2; ++h) {
        // stage W N-half: rows h*128..h*128+127, bf16 direct copy
        #pragma unroll
        for (int it = 0; it < 8; ++it) {
            int t = it * 256 + tid;
            int j = t >> 4, c = t & 15;
            uint4 v = *(const uint4*)(Wb + (size_t)(h * 128 + j) * 128 + c * 8);
            int cs = c ^ (j & 15);
            *(uint4*)(Wlds + j * 128 + cs * 8) = v;
        }
        __syncthreads();

        #pragma unroll
        for (int ks = 0; ks < 4; ++ks) {
            int cidx = ks * 4 + q;
            bf16x8 a = *(const bf16x8*)(Alds + (wave * 16 + r16) * 128 + ((cidx ^ r16) * 8));
            bf16x8 b[8];
            #pragma unroll
            for (int nt = 0; nt < 8; ++nt) {
                int jj = nt * 16 + r16;
                b[nt] = *(const bf16x8*)(Wlds + jj * 128 + ((cidx ^ r16) * 8));
            }
            #pragma unroll
            for (int nt = 0; nt < 8; ++nt)
                acc[h][nt] = __builtin_amdgcn_mfma_f32_16x16x32_bf16(a, b[nt], acc[h][nt], 0, 0, 0);
        }
        __syncthreads();
    }

    // ---- store P bf16 (no relu). C/D: col=lane&15 within 16, row=q*4+reg
    const int row_base = G + wave * 16 + q * 4;
    #pragma unroll
    for (int h = 0; h < 2; ++h)
        #pragma unroll
        for (int nt = 0; nt < 8; ++nt) {
            int col = h * 128 + nt * 16 + r16;
            #pragma unroll
            for (int r = 0; r < 4; ++r)
                P[(size_t)(row_base + r) * 256 + col] = (uint16_t)f2bf(acc[h][nt][r]);
        }
}

// ============================================================================
// combine: out[i] = relu(Pl[self_idx[i]] + 0.1 * sum_k Pr[neigh[i][k]])
// P rows: [256] bf16, Pl = elems 0..127, Pr = 128..255.
// 16 threads/node, thread j owns 8 elems. Gathers are 16 B/lane.
// ============================================================================
template <bool OUT_F32>
__global__ void combine(const uint16_t* __restrict__ P,
                        const int* __restrict__ self_idx,
                        const int* __restrict__ neigh_idx,
                        void* __restrict__ out_, int M)
{
    const int t = blockIdx.x * 256 + threadIdx.x;
    const int i = t >> 4;
    const int j = t & 15;
    if (i >= M) return;

    uint4 sv = *(const uint4*)(P + (size_t)self_idx[i] * 256 + j * 8);

    const int* nrow = neigh_idx + (size_t)i * K_NEI;
    int idx[K_NEI];
    #pragma unroll
    for (int k = 0; k < K_NEI; ++k) idx[k] = nrow[k];

    float s0=0,s1=0,s2=0,s3=0,s4=0,s5=0,s6=0,s7=0;
    #pragma unroll
    for (int k = 0; k < K_NEI; ++k) {
        uint4 v = *(const uint4*)(P + (size_t)idx[k] * 256 + 128 + j * 8);
        s0 += bf2f(v.x & 0xFFFFu); s1 += bf2f(v.x >> 16);
        s2 += bf2f(v.y & 0xFFFFu); s3 += bf2f(v.y >> 16);
        s4 += bf2f(v.z & 0xFFFFu); s5 += bf2f(v.z >> 16);
        s6 += bf2f(v.w & 0xFFFFu); s7 += bf2f(v.w >> 16);
    }
    const float inv = 0.1f;
    float r0 = bf2f(sv.x & 0xFFFFu) + s0 * inv, r1 = bf2f(sv.x >> 16) + s1 * inv;
    float r2 = bf2f(sv.y & 0xFFFFu) + s2 * inv, r3 = bf2f(sv.y >> 16) + s3 * inv;
    float r4 = bf2f(sv.z & 0xFFFFu) + s4 * inv, r5 = bf2f(sv.z >> 16) + s5 * inv;
    float r6 = bf2f(sv.w & 0xFFFFu) + s6 * inv, r7 = bf2f(sv.w >> 16) + s7 * inv;
    r0 = r0 > 0.f ? r0 : 0.f; r1 = r1 > 0.f ? r1 : 0.f;
    r2 = r2 > 0.f ? r2 : 0.f; r3 = r3 > 0.f ? r3 : 0.f;
    r4 = r4 > 0.f ? r4 : 0.f; r5 = r5 > 0.f ? r5 : 0.f;
    r6 = r6 > 0.f ? r6 : 0.f; r7 = r7 > 0.f ? r7 : 0.f;

    if (OUT_F32) {
        float* dst = (float*)out_ + (size_t)i * D + j * 8;
        *(f32x4*)dst       = (f32x4){r0, r1, r2, r3};
        *(f32x4*)(dst + 4) = (f32x4){r4, r5, r6, r7};
    } else {
        uint4 o;
        o.x = pack2(r0, r1); o.y = pack2(r2, r3);
        o.z = pack2(r4, r5); o.w = pack2(r6, r7);
        *(uint4*)((uint16_t*)out_ + (size_t)i * D + j * 8) = o;
    }
}

// ============================================================================
// Fallback path B kernels (R4, proven): build_A + gemm_relu
// ============================================================================
template <bool FEATS_F32>
__global__ void build_A(const void* __restrict__ feats_,
                        const int* __restrict__ self_idx,
                        const int* __restrict__ neigh_idx,
                        uint16_t* __restrict__ A, int M)
{
    const int t = blockIdx.x * 256 + threadIdx.x;
    const int i = t >> 4;
    const int j = t & 15;
    if (i >= M) return;

    const float*    ff = (const float*)feats_;
    const uint16_t* fb = (const uint16_t*)feats_;

    {
        int node = self_idx[i];
        uint4 o;
        if (FEATS_F32) {
            const float* src = ff + (size_t)node * D + j * 8;
            f32x4 a = *(const f32x4*)src;
            f32x4 b = *(const f32x4*)(src + 4);
            o.x = pack2(a[0], a[1]); o.y = pack2(a[2], a[3]);
            o.z = pack2(b[0], b[1]); o.w = pack2(b[2], b[3]);
        } else {
            o = *(const uint4*)(fb + (size_t)node * D + j * 8);
        }
        *(uint4*)(A + (size_t)i * 256 + j * 8) = o;
    }

    const int* nrow = neigh_idx + (size_t)i * K_NEI;
    int idx[K_NEI];
    #pragma unroll
    for (int k = 0; k < K_NEI; ++k) idx[k] = nrow[k];

    float s0=0,s1=0,s2=0,s3=0,s4=0,s5=0,s6=0,s7=0;
    #pragma unroll
    for (int k = 0; k < K_NEI; ++k) {
        if (FEATS_F32) {
            const float* src = ff + (size_t)idx[k] * D + j * 8;
            f32x4 a = *(const f32x4*)src;
            f32x4 b = *(const f32x4*)(src + 4);
            s0 += a[0]; s1 += a[1]; s2 += a[2]; s3 += a[3];
            s4 += b[0]; s5 += b[1]; s6 += b[2]; s7 += b[3];
        } else {
            uint4 v = *(const uint4*)(fb + (size_t)idx[k] * D + j * 8);
            s0 += bf2f(v.x & 0xFFFFu); s1 += bf2f(v.x >> 16);
            s2 += bf2f(v.y & 0xFFFFu); s3 += bf2f(v.y >> 16);
            s4 += bf2f(v.z & 0xFFFFu); s5 += bf2f(v.z >> 16);
            s6 += bf2f(v.w & 0xFFFFu); s7 += bf2f(v.w >> 16);
        }
    }
    const float inv = 0.1f;
    uint4 o;
    o.x = pack2(s0 * inv, s1 * inv);
    o.y = pack2(s2 * inv, s3 * inv);
    o.z = pack2(s4 * inv, s5 * inv);
    o.w = pack2(s6 * inv, s7 * inv);
    *(uint4*)(A + (size_t)i * 256 + 128 + j * 8) = o;
}

template <bool OUT_F32>
__global__ void gemm_relu(const uint16_t* __restrict__ A,
                          const float* __restrict__ W,
                          void* __restrict__ out_)
{
    __shared__ __align__(16) uint16_t Alds[TILE_M * 128];
    __shared__ __align__(16) uint16_t Wlds[128 * 128];

    const int tid  = threadIdx.x;
    const int wave = tid >> 6;
    const int lane = tid & 63;
    const int r16  = lane & 15;
    const int q    = lane >> 4;
    const int G    = blockIdx.x * TILE_M;

    f32x4 acc[8];
    #pragma unroll
    for (int nt = 0; nt < 8; ++nt) acc[nt] = (f32x4){0.f, 0.f, 0.f, 0.f};

    for (int half = 0; half < 2; ++half) {
        #pragma unroll
        for (int it = 0; it < 8; ++it) {
            int t = it * 256 + tid;
            int j = t >> 4, c = t & 15;
            const float* src = W + (size_t)j * 256 + half * 128 + c * 8;
            f32x4 w0 = *(const f32x4*)(src);
            f32x4 w1 = *(const f32x4*)(src + 4);
            uint4 o;
            o.x = pack2(w0[0], w0[1]); o.y = pack2(w0[2], w0[3]);
            o.z = pack2(w1[0], w1[1]); o.w = pack2(w1[2], w1[3]);
            int cs = c ^ (j & 15);
            *(uint4*)(Wlds + j * 128 + cs * 8) = o;
        }
        #pragma unroll
        for (int it = 0; it < 4; ++it) {
            int t = it * 256 + tid;
            int n = t >> 4, c = t & 15;
            uint4 v = *(const uint4*)(A + (size_t)(G + n) * 256 + half * 128 + c * 8);
            int cs = c ^ (n & 15);
            *(uint4*)(Alds + n * 128 + cs * 8) = v;
        }
        __syncthreads();

        #pragma unroll
        for (int ks = 0; ks < 4; ++ks) {
            int cidx = ks * 4 + q;
            bf16x8 a = *(const bf16x8*)(Alds + (wave * 16 + r16) * 128 + ((cidx ^ r16) * 8));
            bf16x8 b[8];
            #pragma unroll
            for (int nt = 0; nt < 8; ++nt) {
                int jj = nt * 16 + r16;
                b[nt] = *(const bf16x8*)(Wlds + jj * 128 + ((cidx ^ r16) * 8));
            }
            #pragma unroll
            for (int nt = 0; nt < 8; ++nt)
                acc[nt] = __builtin_amdgcn_mfma_f32_16x16x32_bf16(a, b[nt], acc[nt], 0, 0, 0);
        }
        __syncthreads();
    }

    const int row_base = G + wave * 16 + q * 4;
    #pragma unroll
    for (int nt = 0; nt < 8; ++nt) {
        int col = nt * 16 + r16;
        #pragma unroll
        for (int r = 0; r < 4; ++r) {
            float v = acc[nt][r];
            v = v > 0.f ? v : 0.f;
            if (OUT_F32) ((float*)out_)[(size_t)(row_base + r) * D + col] = v;
            else ((uint16_t*)out_)[(size_t)(row_base + r) * D + col] = (uint16_t)f2bf(v);
        }
    }
}

extern "C" void kernel_launch(void* const* d_in, const int* in_sizes, int n_in,
                              void* d_out, int out_size, void* d_ws, size_t ws_size,
                              hipStream_t stream) {
    const float* raw = (const float*)d_in[0];          // [200000][128] fp32
    const float* W1  = (const float*)d_in[1];          // [128][256] fp32
    const float* W2  = (const float*)d_in[2];          // [128][256] fp32
    const int* layer1_nodes = (const int*)d_in[3];     // [81920]
    const int* neigh0       = (const int*)d_in[4];     // [81920][10]
    const int* map_batch    = (const int*)d_in[5];     // [8192]
    const int* neigh1       = (const int*)d_in[6];     // [8192][10]

    const int N_NODES = in_sizes[0] / D;   // 200000
    const int N1 = in_sizes[3];            // 81920
    const int B  = in_sizes[5];            // 8192

    // Path A (linear-commute): ws = [P/Q shared: N_NODES*256*2][h1: N1*128*2][W1b][W2b]
    const size_t szP  = (size_t)N_NODES * 256 * 2;
    const size_t szQ  = (size_t)N1 * 256 * 2;
    const size_t szH1 = (size_t)N1 * 128 * 2;
    const size_t szW  = 256 * 128 * 2;
    const size_t needA = (szP > szQ ? szP : szQ) + szH1 + 2 * szW;

    if (ws_size >= needA && (N_NODES % TILE_M) == 0 && (N1 % TILE_M) == 0) {
        uint16_t* Pbuf = (uint16_t*)d_ws;                       // aliased by Q later
        uint16_t* h1   = (uint16_t*)((char*)d_ws + (szP > szQ ? szP : szQ));
        uint16_t* W1b  = h1 + (size_t)N1 * 128;
        uint16_t* W2b  = W1b + 256 * 128;

        convert_W<<<16, 256, 0, stream>>>(W1, W1b);
        convert_W<<<16, 256, 0, stream>>>(W2, W2b);
        // P = raw @ W1b^T  (streaming, all nodes)
        gemm_P<true ><<<N_NODES / TILE_M, 256, 0, stream>>>(raw, W1b, Pbuf);
        // h1 = relu(Pl[self] + mean Pr[nbr])
        combine<false><<<(N1 * 16 + 255) / 256, 256, 0, stream>>>(Pbuf, layer1_nodes, neigh0, h1, N1);
        // Q = h1 @ W2b^T  (aliases P region; P dead)
        gemm_P<false><<<N1 / TILE_M, 256, 0, stream>>>(h1, W2b, Pbuf);
        // out = relu(Ql[map] + mean Qr[nbr1])
        combine<true ><<<(B * 16 + 255) / 256, 256, 0, stream>>>(Pbuf, map_batch, neigh1, d_out, B);
        return;
    }

    // Path B (R4): build_A + gemm
    const size_t needB = (size_t)N1 * 256 * 2 + (size_t)N1 * 128 * 2 + (size_t)B * 256 * 2;
    if (ws_size >= needB) {
        uint16_t* A1 = (uint16_t*)d_ws;
        uint16_t* h1 = A1 + (size_t)N1 * 256;
        uint16_t* A2 = h1 + (size_t)N1 * 128;

        build_A<true ><<<(N1 * 16 + 255) / 256, 256, 0, stream>>>(raw, layer1_nodes, neigh0, A1, N1);
        gemm_relu<false><<<N1 / TILE_M, 256, 0, stream>>>(A1, W1, h1);
        build_A<false><<<(B * 16 + 255) / 256, 256, 0, stream>>>(h1, map_batch, neigh1, A2, B);
        gemm_relu<true ><<<B / TILE_M, 256, 0, stream>>>(A2, W2, d_out);
    }
}

// Round 6
// 243.238 us; speedup vs baseline: 1.0352x; 1.0054x over previous
//
#include <hip/hip_runtime.h>
#include <stdint.h>

#define D 128
#define K_NEI 10
#define TILE_M 64   // fused-fallback tile

typedef __bf16 bf16x8 __attribute__((ext_vector_type(8)));
typedef float f32x4 __attribute__((ext_vector_type(4)));

__device__ __forceinline__ uint32_t f2bf(float f) {
    union { float f; uint32_t u; } v; v.f = f;
    uint32_t u = v.u;
    return (u + 0x7FFFu + ((u >> 16) & 1u)) >> 16;   // RNE
}
__device__ __forceinline__ float bf2f(uint32_t h) {
    union { uint32_t u; float f; } v; v.u = h << 16; return v.f;
}
__device__ __forceinline__ uint32_t pack2(float a, float b) {
    return f2bf(a) | (f2bf(b) << 16);
}
__device__ __forceinline__ bf16x8 u4_as_bf16x8(uint4 u) {
    union { uint4 u; bf16x8 b; } v; v.u = u; return v.b;
}

// ============================================================================
// convert_W2: W1,W2 [128][256] fp32 -> W1b,W2b [256][128] bf16
// Wb[c][k] = W[c & 127][(c>>7)*128 + k]. 32 blocks: 0..15 -> W1, 16..31 -> W2.
// ============================================================================
__global__ void convert_W2(const float* __restrict__ Wa, const float* __restrict__ Wb_in,
                           uint16_t* __restrict__ Oa, uint16_t* __restrict__ Ob)
{
    const float* W = (blockIdx.x < 16) ? Wa : Wb_in;
    uint16_t*    O = (blockIdx.x < 16) ? Oa : Ob;
    int t = (blockIdx.x & 15) * 256 + threadIdx.x;   // 0..4095
    int c = t >> 4, j = t & 15;
    const float* src = W + (size_t)(c & 127) * 256 + (c >> 7) * 128 + j * 8;
    f32x4 a = *(const f32x4*)src;
    f32x4 b = *(const f32x4*)(src + 4);
    uint4 o;
    o.x = pack2(a[0], a[1]); o.y = pack2(a[2], a[3]);
    o.z = pack2(b[0], b[1]); o.w = pack2(b[2], b[3]);
    *(uint4*)(O + (size_t)c * 128 + j * 8) = o;
}

// ============================================================================
// gemm_ws: P[M][256] = A[M][128] @ Wb^T  (bf16 out, no relu)
// W-stationary: all 256x128 bf16 of Wb staged in 64 KB LDS ONCE per block;
// each wave then grid-strides over 16-row tiles with NO barriers:
//   A: global->register (fp32 converted at use), next tile prefetched.
//   B: LDS ds_read_b128, XOR-swizzled (conflict-free, proven R3-R5).
// MFMA 16x16x32: A[m=lane&15][k=q*8+j], C/D col=lane&15, row=q*4+reg.
// ============================================================================
template <bool A_F32>
__global__ __launch_bounds__(256)
void gemm_ws(const void* __restrict__ Asrc_,
             const uint16_t* __restrict__ Wb,
             uint16_t* __restrict__ P, int M)
{
    __shared__ __align__(16) uint16_t Wlds[256 * 128];   // 64 KB

    const int tid  = threadIdx.x;
    const int wave = tid >> 6;
    const int lane = tid & 63;
    const int r16  = lane & 15;
    const int q    = lane >> 4;

    // ---- stage all of Wb once (4096 16B chunks / 256 threads = 16 each)
    #pragma unroll
    for (int it = 0; it < 16; ++it) {
        int t = it * 256 + tid;
        int j = t >> 4, c = t & 15;                      // j: 0..255, c: 0..15
        uint4 v = *(const uint4*)(Wb + (size_t)j * 128 + c * 8);
        int cs = c ^ (j & 15);
        *(uint4*)(Wlds + j * 128 + cs * 8) = v;
    }
    __syncthreads();                                     // only barrier in kernel

    const int nTiles = M >> 4;
    const int stride = gridDim.x * 4;
    int tile = blockIdx.x * 4 + wave;
    if (tile >= nTiles) return;

    // raw prefetch buffers (convert deferred to use so vmcnt waits can sink)
    f32x4 preF[8];  uint4 preB[4];

    // prefetch first tile
    if (A_F32) {
        const float* row = (const float*)Asrc_ + (size_t)(tile * 16 + r16) * D + q * 8;
        #pragma unroll
        for (int ks = 0; ks < 4; ++ks) {
            preF[2 * ks]     = *(const f32x4*)(row + ks * 32);
            preF[2 * ks + 1] = *(const f32x4*)(row + ks * 32 + 4);
        }
    } else {
        const uint16_t* row = (const uint16_t*)Asrc_ + (size_t)(tile * 16 + r16) * D + q * 8;
        #pragma unroll
        for (int ks = 0; ks < 4; ++ks)
            preB[ks] = *(const uint4*)(row + ks * 32);
    }

    while (tile < nTiles) {
        const int nxt = tile + stride;

        // ---- build current A fragments from prefetch buffers
        bf16x8 a[4];
        if (A_F32) {
            #pragma unroll
            for (int ks = 0; ks < 4; ++ks) {
                uint4 u;
                u.x = pack2(preF[2*ks][0],   preF[2*ks][1]);
                u.y = pack2(preF[2*ks][2],   preF[2*ks][3]);
                u.z = pack2(preF[2*ks+1][0], preF[2*ks+1][1]);
                u.w = pack2(preF[2*ks+1][2], preF[2*ks+1][3]);
                a[ks] = u4_as_bf16x8(u);
            }
        } else {
            #pragma unroll
            for (int ks = 0; ks < 4; ++ks) a[ks] = u4_as_bf16x8(preB[ks]);
        }

        // ---- prefetch next tile (loads in flight across the MFMA block)
        if (nxt < nTiles) {
            if (A_F32) {
                const float* row = (const float*)Asrc_ + (size_t)(nxt * 16 + r16) * D + q * 8;
                #pragma unroll
                for (int ks = 0; ks < 4; ++ks) {
                    preF[2 * ks]     = *(const f32x4*)(row + ks * 32);
                    preF[2 * ks + 1] = *(const f32x4*)(row + ks * 32 + 4);
                }
            } else {
                const uint16_t* row = (const uint16_t*)Asrc_ + (size_t)(nxt * 16 + r16) * D + q * 8;
                #pragma unroll
                for (int ks = 0; ks < 4; ++ks)
                    preB[ks] = *(const uint4*)(row + ks * 32);
            }
        }

        // ---- compute: 2 col-halves x 4 k-steps x 8 col-tiles = 64 MFMA
        f32x4 acc[2][8];
        #pragma unroll
        for (int h = 0; h < 2; ++h)
            #pragma unroll
            for (int nt = 0; nt < 8; ++nt) acc[h][nt] = (f32x4){0.f, 0.f, 0.f, 0.f};

        #pragma unroll
        for (int h = 0; h < 2; ++h)
            #pragma unroll
            for (int ks = 0; ks < 4; ++ks) {
                const int cidx = ks * 4 + q;
                #pragma unroll
                for (int nt = 0; nt < 8; ++nt) {
                    const int jj = h * 128 + nt * 16 + r16;
                    bf16x8 b = *(const bf16x8*)(Wlds + jj * 128 + ((cidx ^ r16) * 8));
                    acc[h][nt] = __builtin_amdgcn_mfma_f32_16x16x32_bf16(a[ks], b, acc[h][nt], 0, 0, 0);
                }
            }

        // ---- store 16x256 bf16 tile
        const int row0 = tile * 16 + q * 4;
        #pragma unroll
        for (int h = 0; h < 2; ++h)
            #pragma unroll
            for (int nt = 0; nt < 8; ++nt) {
                const int col = h * 128 + nt * 16 + r16;
                #pragma unroll
                for (int r = 0; r < 4; ++r)
                    P[(size_t)(row0 + r) * 256 + col] = (uint16_t)f2bf(acc[h][nt][r]);
            }

        tile = nxt;
    }
}

// ============================================================================
// combine: out[i] = relu(Pl[self_idx[i]] + 0.1 * sum_k Pr[neigh[i][k]])
// P rows [256] bf16 (Pl=0..127, Pr=128..255). 16 thr/node, 16 B gathers.
// ============================================================================
template <bool OUT_F32>
__global__ void combine(const uint16_t* __restrict__ P,
                        const int* __restrict__ self_idx,
                        const int* __restrict__ neigh_idx,
                        void* __restrict__ out_, int M)
{
    const int t = blockIdx.x * 256 + threadIdx.x;
    const int i = t >> 4;
    const int j = t & 15;
    if (i >= M) return;

    uint4 sv = *(const uint4*)(P + (size_t)self_idx[i] * 256 + j * 8);

    // 10 indices via 5 x int2 (rows are 40 B, 8 B aligned)
    const int2* nrow2 = (const int2*)(neigh_idx + (size_t)i * K_NEI);
    int idx[K_NEI];
    #pragma unroll
    for (int k = 0; k < 5; ++k) {
        int2 p = nrow2[k];
        idx[2 * k] = p.x; idx[2 * k + 1] = p.y;
    }

    float s0=0,s1=0,s2=0,s3=0,s4=0,s5=0,s6=0,s7=0;
    #pragma unroll
    for (int k = 0; k < K_NEI; ++k) {
        uint4 v = *(const uint4*)(P + (size_t)idx[k] * 256 + 128 + j * 8);
        s0 += bf2f(v.x & 0xFFFFu); s1 += bf2f(v.x >> 16);
        s2 += bf2f(v.y & 0xFFFFu); s3 += bf2f(v.y >> 16);
        s4 += bf2f(v.z & 0xFFFFu); s5 += bf2f(v.z >> 16);
        s6 += bf2f(v.w & 0xFFFFu); s7 += bf2f(v.w >> 16);
    }
    const float inv = 0.1f;
    float r0 = bf2f(sv.x & 0xFFFFu) + s0 * inv, r1 = bf2f(sv.x >> 16) + s1 * inv;
    float r2 = bf2f(sv.y & 0xFFFFu) + s2 * inv, r3 = bf2f(sv.y >> 16) + s3 * inv;
    float r4 = bf2f(sv.z & 0xFFFFu) + s4 * inv, r5 = bf2f(sv.z >> 16) + s5 * inv;
    float r6 = bf2f(sv.w & 0xFFFFu) + s6 * inv, r7 = bf2f(sv.w >> 16) + s7 * inv;
    r0 = r0 > 0.f ? r0 : 0.f; r1 = r1 > 0.f ? r1 : 0.f;
    r2 = r2 > 0.f ? r2 : 0.f; r3 = r3 > 0.f ? r3 : 0.f;
    r4 = r4 > 0.f ? r4 : 0.f; r5 = r5 > 0.f ? r5 : 0.f;
    r6 = r6 > 0.f ? r6 : 0.f; r7 = r7 > 0.f ? r7 : 0.f;

    if (OUT_F32) {
        float* dst = (float*)out_ + (size_t)i * D + j * 8;
        *(f32x4*)dst       = (f32x4){r0, r1, r2, r3};
        *(f32x4*)(dst + 4) = (f32x4){r4, r5, r6, r7};
    } else {
        uint4 o;
        o.x = pack2(r0, r1); o.y = pack2(r2, r3);
        o.z = pack2(r4, r5); o.w = pack2(r6, r7);
        *(uint4*)((uint16_t*)out_ + (size_t)i * D + j * 8) = o;
    }
}

// ============================================================================
// Fallback: R3 fused kernel (proven) — only if ws too small for path A.
// ============================================================================
template <bool FEATS_F32, bool OUT_F32>
__global__ void sage_layer(const void* __restrict__ feats_,
                           const float* __restrict__ W,
                           const int* __restrict__ self_idx,
                           const int* __restrict__ neigh_idx,
                           void* __restrict__ out_)
{
    __shared__ __align__(16) uint16_t Alds[TILE_M * 128];
    __shared__ __align__(16) uint16_t Wlds[128 * 128];

    const int tid  = threadIdx.x;
    const int wave = tid >> 6;
    const int lane = tid & 63;
    const int r16  = lane & 15;
    const int q    = lane >> 4;
    const int G    = blockIdx.x * TILE_M;

    const float*    feats_f = (const float*)feats_;
    const uint16_t* feats_b = (const uint16_t*)feats_;

    f32x4 acc[8];
    #pragma unroll
    for (int nt = 0; nt < 8; ++nt) acc[nt] = (f32x4){0.f, 0.f, 0.f, 0.f};

    for (int half = 0; half < 2; ++half) {
        #pragma unroll
        for (int it = 0; it < 8; ++it) {
            int t = it * 256 + tid;
            int j = t >> 4, c = t & 15;
            const float* src = W + (size_t)j * 256 + half * 128 + c * 8;
            f32x4 w0 = *(const f32x4*)(src);
            f32x4 w1 = *(const f32x4*)(src + 4);
            uint4 o;
            o.x = pack2(w0[0], w0[1]); o.y = pack2(w0[2], w0[3]);
            o.z = pack2(w1[0], w1[1]); o.w = pack2(w1[2], w1[3]);
            int cs = c ^ (j & 15);
            *(uint4*)(Wlds + j * 128 + cs * 8) = o;
        }
        if (half == 0) {
            #pragma unroll
            for (int it = 0; it < 4; ++it) {
                int t = it * 256 + tid;
                int n = t >> 4, c = t & 15;
                int node = self_idx[G + n];
                uint4 o;
                if (FEATS_F32) {
                    const float* src = feats_f + (size_t)node * D + c * 8;
                    f32x4 f0 = *(const f32x4*)(src);
                    f32x4 f1 = *(const f32x4*)(src + 4);
                    o.x = pack2(f0[0], f0[1]); o.y = pack2(f0[2], f0[3]);
                    o.z = pack2(f1[0], f1[1]); o.w = pack2(f1[2], f1[3]);
                } else {
                    o = *(const uint4*)(feats_b + (size_t)node * D + c * 8);
                }
                int cs = c ^ (n & 15);
                *(uint4*)(Alds + n * 128 + cs * 8) = o;
            }
        } else {
            #pragma unroll
            for (int it = 0; it < 4; ++it) {
                int t = it * 256 + tid;
                int n = t >> 4, c = t & 15;
                const int* nrow = neigh_idx + (size_t)(G + n) * K_NEI;
                float s0=0,s1=0,s2=0,s3=0,s4=0,s5=0,s6=0,s7=0;
                #pragma unroll
                for (int k = 0; k < K_NEI; ++k) {
                    if (FEATS_F32) {
                        const float* src = feats_f + (size_t)nrow[k] * D + c * 8;
                        f32x4 f0 = *(const f32x4*)(src);
                        f32x4 f1 = *(const f32x4*)(src + 4);
                        s0 += f0[0]; s1 += f0[1]; s2 += f0[2]; s3 += f0[3];
                        s4 += f1[0]; s5 += f1[1]; s6 += f1[2]; s7 += f1[3];
                    } else {
                        uint4 v = *(const uint4*)(feats_b + (size_t)nrow[k] * D + c * 8);
                        s0 += bf2f(v.x & 0xFFFFu); s1 += bf2f(v.x >> 16);
                        s2 += bf2f(v.y & 0xFFFFu); s3 += bf2f(v.y >> 16);
                        s4 += bf2f(v.z & 0xFFFFu); s5 += bf2f(v.z >> 16);
                        s6 += bf2f(v.w & 0xFFFFu); s7 += bf2f(v.w >> 16);
                    }
                }
                const float inv = 0.1f;
                uint4 o;
                o.x = pack2(s0 * inv, s1 * inv);
                o.y = pack2(s2 * inv, s3 * inv);
                o.z = pack2(s4 * inv, s5 * inv);
                o.w = pack2(s6 * inv, s7 * inv);
                int cs = c ^ (n & 15);
                *(uint4*)(Alds + n * 128 + cs * 8) = o;
            }
        }
        __syncthreads();

        #pragma unroll
        for (int ks = 0; ks < 4; ++ks) {
            int cidx = ks * 4 + q;
            bf16x8 a = *(const bf16x8*)(Alds + (wave * 16 + r16) * 128 + ((cidx ^ r16) * 8));
            bf16x8 b[8];
            #pragma unroll
            for (int nt = 0; nt < 8; ++nt) {
                int jj = nt * 16 + r16;
                b[nt] = *(const bf16x8*)(Wlds + jj * 128 + ((cidx ^ r16) * 8));
            }
            #pragma unroll
            for (int nt = 0; nt < 8; ++nt)
                acc[nt] = __builtin_amdgcn_mfma_f32_16x16x32_bf16(a, b[nt], acc[nt], 0, 0, 0);
        }
        __syncthreads();
    }

    const int row_base = G + wave * 16 + q * 4;
    #pragma unroll
    for (int nt = 0; nt < 8; ++nt) {
        int col = nt * 16 + r16;
        #pragma unroll
        for (int r = 0; r < 4; ++r) {
            float v = acc[nt][r];
            v = v > 0.f ? v : 0.f;
            if (OUT_F32) ((float*)out_)[(size_t)(row_base + r) * D + col] = v;
            else ((uint16_t*)out_)[(size_t)(row_base + r) * D + col] = (uint16_t)f2bf(v);
        }
    }
}

extern "C" void kernel_launch(void* const* d_in, const int* in_sizes, int n_in,
                              void* d_out, int out_size, void* d_ws, size_t ws_size,
                              hipStream_t stream) {
    const float* raw = (const float*)d_in[0];          // [200000][128] fp32
    const float* W1  = (const float*)d_in[1];          // [128][256] fp32
    const float* W2  = (const float*)d_in[2];          // [128][256] fp32
    const int* layer1_nodes = (const int*)d_in[3];     // [81920]
    const int* neigh0       = (const int*)d_in[4];     // [81920][10]
    const int* map_batch    = (const int*)d_in[5];     // [8192]
    const int* neigh1       = (const int*)d_in[6];     // [8192][10]

    const int N_NODES = in_sizes[0] / D;   // 200000
    const int N1 = in_sizes[3];            // 81920
    const int B  = in_sizes[5];            // 8192

    const size_t szP  = (size_t)N_NODES * 256 * 2;
    const size_t szQ  = (size_t)N1 * 256 * 2;
    const size_t szH1 = (size_t)N1 * 128 * 2;
    const size_t szW  = 256 * 128 * 2;
    const size_t needA = (szP > szQ ? szP : szQ) + szH1 + 2 * szW;

    if (ws_size >= needA && (N_NODES % 16) == 0 && (N1 % 16) == 0 && (B % 16) == 0) {
        uint16_t* Pbuf = (uint16_t*)d_ws;                       // P, later aliased by Q
        uint16_t* h1   = (uint16_t*)((char*)d_ws + (szP > szQ ? szP : szQ));
        uint16_t* W1b  = h1 + (size_t)N1 * 128;
        uint16_t* W2b  = W1b + 256 * 128;

        convert_W2<<<32, 256, 0, stream>>>(W1, W2, W1b, W2b);

        int tiles1 = N_NODES >> 4;                              // 12500
        int grid1  = 1024;                                      // grid-stride, ~3 tiles/wave
        gemm_ws<true ><<<grid1, 256, 0, stream>>>(raw, W1b, Pbuf, N_NODES);

        combine<false><<<(N1 * 16 + 255) / 256, 256, 0, stream>>>(Pbuf, layer1_nodes, neigh0, h1, N1);

        int tiles2 = N1 >> 4;                                   // 5120
        int grid2  = (tiles2 + 3) / 4;                          // 1280: exactly 1 tile/wave
        if (grid2 > 1280) grid2 = 1280;
        gemm_ws<false><<<grid2, 256, 0, stream>>>(h1, W2b, Pbuf, N1);

        combine<true ><<<(B * 16 + 255) / 256, 256, 0, stream>>>(Pbuf, map_batch, neigh1, d_out, B);
        return;
    }

    // Fallback: R3 fused path
    uint16_t* h1 = (uint16_t*)d_ws;
    sage_layer<true,  false><<<N1 / TILE_M, 256, 0, stream>>>(raw, W1, layer1_nodes, neigh0, h1);
    sage_layer<false, true ><<<B  / TILE_M, 256, 0, stream>>>(h1,  W2, map_batch,    neigh1, d_out);
}